// Round 3
// baseline (137.012 us; speedup 1.0000x reference)
//
#include <hip/hip_runtime.h>

#define N 8192
#define D 256
#define BM 128   // rows and cols per block tile

typedef short short8 __attribute__((ext_vector_type(8)));
typedef float f32x4 __attribute__((ext_vector_type(4)));

__device__ __forceinline__ unsigned short f2bf(float f) {
    unsigned int u = __float_as_uint(f);
    u += 0x7fffu + ((u >> 16) & 1u);   // RNE
    return (unsigned short)(u >> 16);
}
__device__ __forceinline__ float bf2f(unsigned short h) {
    return __uint_as_float(((unsigned int)h) << 16);
}

// async global->LDS, 16B per lane; dst is wave-uniform base, lane i lands at dst + i*16
#define GLDS16(g, l) __builtin_amdgcn_global_load_lds(                      \
    (const __attribute__((address_space(1))) void*)(g),                     \
    (__attribute__((address_space(3))) void*)(l), 16, 0, 0)

// Kernel 0: fp32 -> bf16 pre-conversion + row squared norms (of bf16-rounded
// values, consistent with the MFMA Gram) + zero the S/L accumulators.
__global__ __launch_bounds__(256) void k_cvt(const float* __restrict__ x,
                                             unsigned short* __restrict__ xb,
                                             float* __restrict__ sq,
                                             float* __restrict__ Sarr,
                                             float* __restrict__ Larr) {
    const int wv = threadIdx.x >> 6, lane = threadIdx.x & 63;
    const int row = blockIdx.x * 4 + wv;
    const float4 v = ((const float4*)x)[(size_t)row * 64 + lane];
    unsigned short pa = f2bf(v.x), pb = f2bf(v.y), pc = f2bf(v.z), pd = f2bf(v.w);
    float a = bf2f(pa), b = bf2f(pb), c = bf2f(pc), d = bf2f(pd);
    float s = a * a + b * b + c * c + d * d;
    ((ushort4*)xb)[(size_t)row * 64 + lane] = make_ushort4(pa, pb, pc, pd);
#pragma unroll
    for (int m = 1; m < 64; m <<= 1) s += __shfl_xor(s, m, 64);
    if (lane == 0) {
        sq[row] = s;
        Sarr[row] = 0.0f;
        Larr[row] = 0.0f;
    }
}

// Kernel 1: SYMMETRIC Gram. Only upper-triangular 128x128 block tiles
// (2080 of 4096). A (128 rows x K=256) in registers (32 rows/wave); the whole
// 128-col B tile staged ONCE into 64 KB LDS via global_load_lds (single
// barrier per block). Off-diagonal blocks commit both row-sums and col-sums
// (symmetry); diagonal blocks commit rows only. Per row: S = sum k,
// L = sum k*ln k with ln k = -d2/2T^2 (no log in the inner loop).
__global__ __launch_bounds__(256, 2) void k_gram(const unsigned short* __restrict__ xb,
                                                 const float* __restrict__ sq,
                                                 const float* __restrict__ temp,
                                                 float* __restrict__ Sarr,
                                                 float* __restrict__ Larr) {
    __shared__ unsigned short Bs[BM * D];   // 64 KB, 16B-chunk XOR swizzled

    const int tid = threadIdx.x;
    const int wv = tid >> 6, lane = tid & 63;
    const int q8 = lane >> 4, c = lane & 15;

    // triangular block decode: b -> (p, qblk), p <= qblk, C(p) = 64p - p(p-1)/2
    const int b = blockIdx.x;
    int p = (int)((129.0f - sqrtf(16641.0f - 8.0f * (float)b)) * 0.5f);
    while (64 * p - (p * (p - 1)) / 2 > b) --p;
    while (64 * (p + 1) - ((p + 1) * p) / 2 <= b) ++p;
    const int qblk = p + (b - (64 * p - (p * (p - 1)) / 2));
    const int rowbase = p * BM, colbase = qblk * BM;

    // stage the full B tile: 128 rows x 256 shorts; source chunk XOR'd so that
    // LDS[r][slot] = src[r][slot ^ (r&7)] -> bank-balanced fragment reads
    const int rhalf = lane >> 5, slot = lane & 31;
#pragma unroll
    for (int i = 0; i < 16; ++i) {
        int seg = wv * 16 + i;                 // 1 KB segment = 2 rows
        int row = seg * 2 + rhalf;
        int g = slot ^ (row & 7);
        GLDS16(xb + (size_t)(colbase + row) * D + g * 8, Bs + seg * 512);
    }

    // A fragments in registers: wave wv owns rows rowbase + wv*32 .. +31
    short8 av[2][8];
#pragma unroll
    for (int tr = 0; tr < 2; ++tr) {
        const unsigned short* ap = xb + (size_t)(rowbase + wv * 32 + tr * 16 + c) * D;
#pragma unroll
        for (int kk = 0; kk < 8; ++kk)
            av[tr][kk] = *(const short8*)(ap + kk * 32 + q8 * 8);
    }

    float sqr[8];
#pragma unroll
    for (int tr = 0; tr < 2; ++tr)
#pragma unroll
        for (int r = 0; r < 4; ++r)
            sqr[tr * 4 + r] = sq[rowbase + wv * 32 + tr * 16 + q8 * 4 + r];
    float scq[8];
#pragma unroll
    for (int i = 0; i < 8; ++i)
        scq[i] = sq[colbase + (i >> 2) * 64 + (i & 3) * 16 + c];

    const float T = temp[0];
    const float inv2T2 = 1.0f / (2.0f * T * T);
    const int rx = c & 7;

    float Sr[8], Mr[8], Sc[8], Mc[8];
#pragma unroll
    for (int i = 0; i < 8; ++i) { Sr[i] = 0.f; Mr[i] = 0.f; Sc[i] = 0.f; Mc[i] = 0.f; }

    __syncthreads();   // staging complete (vmcnt drained at barrier)

#pragma unroll
    for (int jt = 0; jt < 2; ++jt) {           // two 64-col passes over LDS
        f32x4 acc[2][4];
#pragma unroll
        for (int tr = 0; tr < 2; ++tr)
#pragma unroll
            for (int tc = 0; tc < 4; ++tc)
#pragma unroll
                for (int r = 0; r < 4; ++r) acc[tr][tc][r] = 0.0f;

#pragma unroll
        for (int kk = 0; kk < 8; ++kk) {
            short8 bv[4];
#pragma unroll
            for (int tc = 0; tc < 4; ++tc)
                bv[tc] = *(const short8*)(Bs + (jt * 64 + tc * 16 + c) * D +
                                          (((4 * kk + q8) ^ rx) << 3));
#pragma unroll
            for (int tr = 0; tr < 2; ++tr)
#pragma unroll
                for (int tc = 0; tc < 4; ++tc)
                    acc[tr][tc] = __builtin_amdgcn_mfma_f32_16x16x32_bf16(
                        av[tr][kk], bv[tc], acc[tr][tc], 0, 0, 0);
        }

        // fused epilogue: d2 -> exp -> row and col partial sums
#pragma unroll
        for (int tr = 0; tr < 2; ++tr)
#pragma unroll
            for (int tc = 0; tc < 4; ++tc)
#pragma unroll
                for (int r = 0; r < 4; ++r) {
                    float g = acc[tr][tc][r];
                    float d2 = fmaxf(sqr[tr * 4 + r] + scq[jt * 4 + tc] - 2.0f * g, 0.0f);
                    float t = -d2 * inv2T2;    // = ln k
                    float e = __expf(t);       // = k
                    Sr[tr * 4 + r] += e;
                    Mr[tr * 4 + r] = fmaf(e, t, Mr[tr * 4 + r]);
                    Sc[jt * 4 + tc] += e;
                    Mc[jt * 4 + tc] = fmaf(e, t, Mc[jt * 4 + tc]);
                }
    }

    // commit row sums: reduce across the 16 col-lanes (lane bits 0..3)
#pragma unroll
    for (int m = 1; m <= 8; m <<= 1)
#pragma unroll
        for (int i = 0; i < 8; ++i) {
            Sr[i] += __shfl_xor(Sr[i], m, 64);
            Mr[i] += __shfl_xor(Mr[i], m, 64);
        }
    if (c == 0) {
#pragma unroll
        for (int i = 0; i < 8; ++i) {
            int row = rowbase + wv * 32 + (i >> 2) * 16 + q8 * 4 + (i & 3);
            atomicAdd(&Sarr[row], Sr[i]);
            atomicAdd(&Larr[row], Mr[i]);
        }
    }

    // commit col sums (symmetric counterpart) for off-diagonal blocks only:
    // reduce across the 4 row-quads (lane bits 4..5)
    if (p != qblk) {
#pragma unroll
        for (int m = 16; m <= 32; m <<= 1)
#pragma unroll
            for (int i = 0; i < 8; ++i) {
                Sc[i] += __shfl_xor(Sc[i], m, 64);
                Mc[i] += __shfl_xor(Mc[i], m, 64);
            }
        if (q8 == 0) {
#pragma unroll
            for (int i = 0; i < 8; ++i) {
                int col = colbase + (i >> 2) * 64 + (i & 3) * 16 + c;
                atomicAdd(&Sarr[col], Sc[i]);
                atomicAdd(&Larr[col], Mc[i]);
            }
        }
    }
}

// Kernel 2 (merged ctrl+scale): per row H = log(S) - L/S,
// cs = sigmoid(-(H - target)/T); write scaled features + control signal.
__global__ __launch_bounds__(256) void k_finish(const float* __restrict__ x,
                                                const float* __restrict__ Sarr,
                                                const float* __restrict__ Larr,
                                                const float* __restrict__ target,
                                                const float* __restrict__ temp,
                                                float* __restrict__ out) {
    const int gid = blockIdx.x * 256 + threadIdx.x;  // float4 index
    const int row = gid >> 6;                        // 64 float4 per row
    float S = Sarr[row], L = Larr[row];
    float H = __logf(S) - L / S;
    float z = (H - target[0]) / temp[0];
    float cs = 1.0f / (1.0f + __expf(z));
    float4 v = ((const float4*)x)[gid];
    float4 o;
    o.x = v.x * cs; o.y = v.y * cs; o.z = v.z * cs; o.w = v.w * cs;
    ((float4*)out)[gid] = o;
    if ((gid & 63) == 0) out[(size_t)N * D + row] = cs;  // control_signal section
}

extern "C" void kernel_launch(void* const* d_in, const int* in_sizes, int n_in,
                              void* d_out, int out_size, void* d_ws, size_t ws_size,
                              hipStream_t stream) {
    const float* x = (const float*)d_in[0];       // features [4,2048,256]
    const float* target = (const float*)d_in[7];  // target_entropy [1]
    const float* temp = (const float*)d_in[8];    // temperature [1]
    float* out = (float*)d_out;

    float* wsf = (float*)d_ws;
    float* sq = wsf;
    float* Sarr = wsf + N;
    float* Larr = wsf + 2 * N;

    // bf16 copy of X: in ws if it fits, else park it in d_out's first 4 MB
    // (k_finish only writes d_out after k_gram has fully consumed xb)
    const size_t need = 3 * (size_t)N * sizeof(float) + (size_t)N * D * sizeof(unsigned short);
    unsigned short* xb = (ws_size >= need) ? (unsigned short*)(wsf + 3 * N)
                                           : (unsigned short*)d_out;

    k_cvt<<<N / 4, 256, 0, stream>>>(x, xb, sq, Sarr, Larr);
    k_gram<<<2080, 256, 0, stream>>>(xb, sq, temp, Sarr, Larr);
    k_finish<<<(N * (D / 4)) / 256, 256, 0, stream>>>(x, Sarr, Larr, target, temp, out);
}